// Round 6
// baseline (253.186 us; speedup 1.0000x reference)
//
#include <hip/hip_runtime.h>
#include <math.h>

// AdaptedMixer — Round 19: stage-count reduction (9 -> 7 dispatches).
//  - memset fused into prep (cvt X, cvt W1, zero ssmp in one launch).
//  - k5b deleted: k5c computes its own carry-in by scanning P/Sf of chunks
//    < c (<=63 indep float4-pair loads + fma chain; ~2 us worst block).
//    Kills the k5b dispatch + boundary + 12.6 MB CIn round-trip.
//  - yh overlays dead Xh/W1h (SfArr stays live for k5c carry reads).
//  - all kernel interiors identical to R18 (best: 242.9 us).
// B=2 S=2048 Dm=768 I=1536 N=16 R=48 K=4.  M = B*S = 4096.

static constexpr int S_LEN  = 2048;
static constexpr int DMODEL = 768;
static constexpr int ICH    = 1536;
static constexpr int NST    = 16;
static constexpr int MROWS  = 4096;   // B*S
static constexpr int NCH    = 64;     // scan chunks
static constexpr int CHS    = 32;     // steps per chunk
static constexpr int CSTR   = 2 * ICH * NST;   // 49152: per-chunk summary stride

typedef _Float16 f16;
typedef f16 f16x8 __attribute__((ext_vector_type(8)));
typedef f16 f16x4 __attribute__((ext_vector_type(4)));
typedef f16 f16x2 __attribute__((ext_vector_type(2)));
typedef float f32x4 __attribute__((ext_vector_type(4)));

#if __has_builtin(__builtin_amdgcn_exp2f)
#define EXP2F(x) __builtin_amdgcn_exp2f(x)
#else
#define EXP2F(x) exp2f(x)
#endif

typedef __attribute__((address_space(3))) void lds_void;
typedef const __attribute__((address_space(1))) void glb_void;

__device__ __forceinline__ void glds16(f16* l, const f16* g) {
    __builtin_amdgcn_global_load_lds((glb_void*)g, (lds_void*)l, 16, 0, 0);
}

__device__ __forceinline__ float silu_f(float x) {
    return x / (1.0f + __expf(-x));
}

// ---------------- prep: cvt X->f16, cvt W1->f16, zero ssmp — one launch.
__global__ __launch_bounds__(256) void prep(
    const float* __restrict__ s0, f16* __restrict__ d0, int n0,
    const float* __restrict__ s1, f16* __restrict__ d1, int n1,
    float* __restrict__ z)          // ssmp, nz floats (exact tail)
{
    int i = (blockIdx.x * 256 + threadIdx.x) * 4;
    if (i < n0) {
        float4 v = *(const float4*)(s0 + i);
        f16x4 o = { (f16)v.x, (f16)v.y, (f16)v.z, (f16)v.w };
        *(f16x4*)(d0 + i) = o;
    } else if (i < n0 + n1) {
        int j = i - n0;
        float4 v = *(const float4*)(s1 + j);
        f16x4 o = { (f16)v.x, (f16)v.y, (f16)v.z, (f16)v.w };
        *(f16x4*)(d1 + j) = o;
    } else {
        int j = i - n0 - n1;
        float4 zv = {};
        *(float4*)(z + j) = zv;
    }
}

// ---------------- K1: in_proj fp16 MFMA GEMM [4096,768] @ [3072,768]^T
// tile 128m x 128n (grid 32x24 = 768 blocks, 3/CU); BK=32 double-buffered
// 2-phase prefetch; waves 2x2, each 64m x 64n, acc[4][4].
__global__ __launch_bounds__(256) void k1m(
    const f16* __restrict__ Xh,    // [4096][768]
    const f16* __restrict__ Wh,    // [3072][768]
    f16* __restrict__ hidden,      // [M][I]
    f16* __restrict__ sgate)       // [M][I] (silu applied)
{
    __shared__ __align__(16) f16 As[2][128 * 32];
    __shared__ __align__(16) f16 Bs[2][128 * 32];
    const int tid = threadIdx.x;
    const int lane = tid & 63, wave = tid >> 6;
    const int quad = lane >> 4, l16 = lane & 15;
    const int wm = wave & 1, wn = wave >> 1;   // wn in 0..1
    const int m0 = blockIdx.x * 128, n0 = blockIdx.y * 128;
    const int l_row = lane >> 2, l_c8 = (lane & 3) * 8;

    const f16* Ag = Xh + (size_t)(m0 + wave * 16 + l_row) * 768 + l_c8;
    const f16* Bg = Wh + (size_t)(n0 + wave * 16 + l_row) * 768 + l_c8;
    const int sLo = (wave * 16) * 32, sHi = (64 + wave * 16) * 32;

#define K1_STAGE(buf, kk)                                        \
    do {                                                         \
        glds16(&As[buf][sLo], Ag + (kk));                        \
        glds16(&As[buf][sHi], Ag + (size_t)64 * 768 + (kk));     \
        glds16(&Bs[buf][sLo], Bg + (kk));                        \
        glds16(&Bs[buf][sHi], Bg + (size_t)64 * 768 + (kk));     \
    } while (0)

#define K1_COMPUTE(buf)                                                        \
    do {                                                                       \
        f16x8 af[4], bf[4];                                                    \
        _Pragma("unroll")                                                      \
        for (int mi = 0; mi < 4; ++mi)                                         \
            af[mi] = *(const f16x8*)&As[buf][(wm * 64 + mi * 16 + l16) * 32 + quad * 8]; \
        _Pragma("unroll")                                                      \
        for (int ni = 0; ni < 4; ++ni)                                         \
            bf[ni] = *(const f16x8*)&Bs[buf][(wn * 64 + ni * 16 + l16) * 32 + quad * 8]; \
        _Pragma("unroll")                                                      \
        for (int mi = 0; mi < 4; ++mi)                                         \
            _Pragma("unroll")                                                  \
            for (int ni = 0; ni < 4; ++ni)                                     \
                acc[mi][ni] = __builtin_amdgcn_mfma_f32_16x16x32_f16(          \
                    af[mi], bf[ni], acc[mi][ni], 0, 0, 0);                     \
    } while (0)

    // prologue: stage k=0..31 into buf0, drain
    K1_STAGE(0, 0);
    __syncthreads();

    f32x4 acc[4][4] = {};
    for (int k0 = 0; k0 < 768; k0 += 64) {
        K1_STAGE(1, k0 + 32);
        K1_COMPUTE(0);
        __syncthreads();           // vmcnt(0): buf1 ready; all waves done with buf0
        if (k0 + 64 < 768) K1_STAGE(0, k0 + 64);
        K1_COMPUTE(1);
        __syncthreads();           // vmcnt(0): buf0 ready; all waves done with buf1
    }
#undef K1_STAGE
#undef K1_COMPUTE

    const bool isGate = (n0 >= ICH);   // n0 multiple of 128; boundary at 1536
    f16* outp = isGate ? sgate : hidden;
    const int e0 = (isGate ? (n0 - ICH) : n0) + wn * 64 + l16;
    #pragma unroll
    for (int mi = 0; mi < 4; ++mi) {
        #pragma unroll
        for (int ni = 0; ni < 4; ++ni) {
            #pragma unroll
            for (int r = 0; r < 4; ++r) {
                int m = m0 + wm * 64 + mi * 16 + quad * 4 + r;
                int e = e0 + ni * 16;
                float v = acc[mi][ni][r];
                if (isGate) v = silu_f(v);
                outp[(size_t)m * ICH + e] = (f16)v;
            }
        }
    }
}

// ---------------- K3: conv+bias+silu fused into A-stage, emits h; then
// x_proj fp16 MFMA GEMM -> ssmp[m][e] (+=, atomics), ksplit x16.
__global__ __launch_bounds__(256) void k3m(
    const f16* __restrict__ hidden,   // [M][I] f16 (pre-conv)
    const float* __restrict__ conv_w, // [I][4]
    const float* __restrict__ conv_b, // [I]
    const float* __restrict__ xw,     // [80][I] fp32
    f16* __restrict__ h,              // [M][I] f16 out (post conv+silu)
    float* __restrict__ ssmp)         // [M][80], pre-zeroed
{
    __shared__ __align__(16) f16 Ah[128 * 32];
    __shared__ __align__(16) f16 Bh[80 * 32];
    __shared__ float4 cwv[96];
    __shared__ float  cbv[96];
    const int tid = threadIdx.x;
    const int lane = tid & 63, wave = tid >> 6;
    const int quad = lane >> 4, l16 = lane & 15;
    const int m0 = blockIdx.x * 128;
    const int kbeg = blockIdx.y * 96;

    if (tid < 96) {
        cwv[tid] = *(const float4*)(conv_w + (size_t)(kbeg + tid) * 4);
        cbv[tid] = conv_b[kbeg + tid];
    }

    f32x4 acc[2][5] = {};
    for (int k0 = kbeg; k0 < kbeg + 96; k0 += 32) {
        __syncthreads();
        // ---- A-stage: compute h = silu(conv(hidden)+b) for 128 rows x 32 ch,
        // write to LDS (MFMA A operand) and to global h.
        #pragma unroll
        for (int it = 0; it < 2; ++it) {
            int slot = tid + it * 256;            // 512 slots: 128 rows x 4 col8
            int r_ = slot >> 2, c_ = (slot & 3) * 8;
            int gm = m0 + r_, c = k0 + c_;
            int s = gm & (S_LEN - 1);
            const f16* bp = hidden + (size_t)gm * ICH + c;
            f16x8 x0 = *(const f16x8*)bp;
            f16x8 x1 = *(const f16x8*)(bp - (s >= 1 ? ICH : 0));
            f16x8 x2 = *(const f16x8*)(bp - (s >= 2 ? 2 * ICH : 0));
            f16x8 x3 = *(const f16x8*)(bp - (s >= 3 ? 3 * ICH : 0));
            f16x8 o;
            #pragma unroll
            for (int j = 0; j < 8; ++j) {
                int ci = (k0 - kbeg) + c_ + j;
                float4 w = cwv[ci];
                float v1 = (s >= 1) ? (float)x1[j] : 0.f;
                float v2 = (s >= 2) ? (float)x2[j] : 0.f;
                float v3 = (s >= 3) ? (float)x3[j] : 0.f;
                float r = cbv[ci] + w.x * v3 + w.y * v2 + w.z * v1 + w.w * (float)x0[j];
                o[j] = (f16)silu_f(r);
            }
            *(f16x8*)&Ah[r_ * 32 + c_] = o;
            *(f16x8*)(h + (size_t)gm * ICH + c) = o;
        }
        // ---- B-stage: 80 rows x 32 cols fp32 -> f16
        {
            int c4 = (tid & 7) * 4;
            for (int r = tid >> 3; r < 80; r += 32) {
                float4 v = *(const float4*)(xw + (size_t)r * ICH + k0 + c4);
                f16x4 o = { (f16)v.x, (f16)v.y, (f16)v.z, (f16)v.w };
                *(f16x4*)&Bh[r * 32 + c4] = o;
            }
        }
        __syncthreads();
        f16x8 af[2], bf[5];
        #pragma unroll
        for (int mi = 0; mi < 2; ++mi)
            af[mi] = *(const f16x8*)&Ah[(wave * 32 + mi * 16 + l16) * 32 + quad * 8];
        #pragma unroll
        for (int j = 0; j < 5; ++j)
            bf[j] = *(const f16x8*)&Bh[(j * 16 + l16) * 32 + quad * 8];
        #pragma unroll
        for (int mi = 0; mi < 2; ++mi)
            #pragma unroll
            for (int j = 0; j < 5; ++j)
                acc[mi][j] = __builtin_amdgcn_mfma_f32_16x16x32_f16(
                    af[mi], bf[j], acc[mi][j], 0, 0, 0);
    }
    #pragma unroll
    for (int mi = 0; mi < 2; ++mi) {
        #pragma unroll
        for (int j = 0; j < 5; ++j) {
            #pragma unroll
            for (int r = 0; r < 4; ++r) {
                int m = m0 + wave * 32 + mi * 16 + quad * 4 + r;
                atomicAdd(ssmp + (size_t)m * 80 + j * 16 + l16, acc[mi][j][r]);
            }
        }
    }
}

// ---------------- K4: dt = softplus(ts @ dtw^T + b) via fp16 MFMA, K=48 padded to 64.
__global__ __launch_bounds__(256) void k4m(
    const float* __restrict__ ssmp,   // [M][80] (ts = cols 0..47)
    const float* __restrict__ dtw,    // [I][48]
    const float* __restrict__ dtb,    // [I]
    const float* __restrict__ alpha,  // [I]
    f16* __restrict__ dt)             // [M][I] f16
{
    __shared__ __align__(16) f16 As[128 * 72];   // [row][72] (64 K + 8 pad)
    __shared__ __align__(16) f16 Bs[128 * 72];
    const int tid = threadIdx.x;
    const int lane = tid & 63, wave = tid >> 6;
    const int quad = lane >> 4, l16 = lane & 15;
    const int wm = wave & 1, wn = wave >> 1;
    const int m0 = blockIdx.x * 128, n0 = blockIdx.y * 128;
    const int srow = tid >> 1;          // 0..127
    const int shalf = tid & 1;          // 0..1 -> cols [0,24) or [24,48)

    {   // stage A (ts) and B (dtw), cvt to fp16, zero-pad cols 48..63
        const float* sa = ssmp + (size_t)(m0 + srow) * 80 + shalf * 24;
        const float* sb = dtw + (size_t)(n0 + srow) * 48 + shalf * 24;
        f16* da = &As[srow * 72 + shalf * 24];
        f16* db = &Bs[srow * 72 + shalf * 24];
        #pragma unroll
        for (int j = 0; j < 6; ++j) {
            float4 va = *(const float4*)(sa + 4 * j);
            float4 vb = *(const float4*)(sb + 4 * j);
            f16x4 oa = { (f16)va.x, (f16)va.y, (f16)va.z, (f16)va.w };
            f16x4 ob = { (f16)vb.x, (f16)vb.y, (f16)vb.z, (f16)vb.w };
            *(f16x4*)(da + 4 * j) = oa;
            *(f16x4*)(db + 4 * j) = ob;
        }
        if (shalf) {
            f16x8 z = {};
            *(f16x8*)&As[srow * 72 + 48] = z;
            *(f16x8*)&As[srow * 72 + 56] = z;
            *(f16x8*)&Bs[srow * 72 + 48] = z;
            *(f16x8*)&Bs[srow * 72 + 56] = z;
        }
    }
    __syncthreads();

    f32x4 acc[4][4] = {};
    #pragma unroll
    for (int ks = 0; ks < 2; ++ks) {
        f16x8 af[4], bf[4];
        #pragma unroll
        for (int mi = 0; mi < 4; ++mi)
            af[mi] = *(const f16x8*)&As[(wm * 64 + mi * 16 + l16) * 72 + ks * 32 + quad * 8];
        #pragma unroll
        for (int ni = 0; ni < 4; ++ni)
            bf[ni] = *(const f16x8*)&Bs[(wn * 64 + ni * 16 + l16) * 72 + ks * 32 + quad * 8];
        #pragma unroll
        for (int mi = 0; mi < 4; ++mi)
            #pragma unroll
            for (int ni = 0; ni < 4; ++ni)
                acc[mi][ni] = __builtin_amdgcn_mfma_f32_16x16x32_f16(
                    af[mi], bf[ni], acc[mi][ni], 0, 0, 0);
    }

    #pragma unroll
    for (int ni = 0; ni < 4; ++ni) {
        int e = n0 + wn * 64 + ni * 16 + l16;
        float bias = dtb[e];
        float al = alpha[e];
        #pragma unroll
        for (int mi = 0; mi < 4; ++mi) {
            #pragma unroll
            for (int r = 0; r < 4; ++r) {
                int m = m0 + wm * 64 + mi * 16 + quad * 4 + r;
                float x = acc[mi][ni][r] + bias;
                float sp = (x > 20.0f) ? x : __logf(1.0f + __expf(x));
                if ((m & (S_LEN - 1)) == S_LEN - 1) sp *= al;
                dt[(size_t)m * ICH + e] = (f16)sp;
            }
        }
    }
}

// ---------------- K5a: per-chunk summary, LDS-staged dt/h/B; coalesced float4 P/Sf.
__global__ __launch_bounds__(256) void k5a_chunk(
    const f16* __restrict__ dt,      // [M][I] f16
    const f16* __restrict__ h,       // [M][I] f16
    const float* __restrict__ ssmp,  // [M][80]: B cols 48..63
    const float* __restrict__ A_log, // [I][16]
    float* __restrict__ PArr,        // [NCH][B*I*16]
    float* __restrict__ SfArr)       // [NCH][B*I*16]
{
    __shared__ float dts[CHS * 64];
    __shared__ float hs[CHS * 64];
    __shared__ float Bc[CHS][16];
    const int tid = threadIdx.x;
    const int n4 = tid & 3;
    const int il = tid >> 2;         // 0..63
    const int i0 = blockIdx.x * 64;
    const int i = i0 + il;
    const int c = blockIdx.y;
    const int b = blockIdx.z;
    const int s0 = c * CHS;
    const size_t row0 = (size_t)(b * S_LEN + s0) * ICH + i0;

    {   // stage dt/h: 32 rows x 64 ch, f16x8 per thread (16B/lane)
        int r = tid >> 3, c8 = (tid & 7) * 8;
        size_t g_off = row0 + (size_t)r * ICH + c8;
        f16x8 dv = *(const f16x8*)(dt + g_off);
        f16x8 hv = *(const f16x8*)(h + g_off);
        #pragma unroll
        for (int j = 0; j < 8; ++j) {
            dts[r * 64 + c8 + j] = (float)dv[j];
            hs[r * 64 + c8 + j]  = (float)hv[j];
        }
    }
    if (tid < CHS * 4) {     // stage B rows: 32 t x 16 floats
        int t = tid >> 2, q = tid & 3;
        *(float4*)&Bc[t][q * 4] =
            *(const float4*)(ssmp + (size_t)(b * S_LEN + s0 + t) * 80 + 48 + q * 4);
    }

    const float L2E = 1.44269504088896f;
    float4 alv = *(const float4*)(A_log + i * NST + n4 * 4);
    float A[4] = { -__expf(alv.x) * L2E, -__expf(alv.y) * L2E,
                   -__expf(alv.z) * L2E, -__expf(alv.w) * L2E };
    float st[4] = {};
    float cdt = 0.f;
    __syncthreads();
    #pragma unroll 4
    for (int t = 0; t < CHS; ++t) {
        float dtv = dts[t * 64 + il];
        float hv  = hs[t * 64 + il];
        float4 Bv = *(const float4*)&Bc[t][n4 * 4];
        cdt += dtv;
        float x = dtv * hv;
        #pragma unroll
        for (int j = 0; j < 4; ++j) {
            float dA = EXP2F(A[j] * dtv);
            st[j] = fmaf(dA, st[j], x * (&Bv.x)[j]);
        }
    }
    size_t base = (size_t)c * CSTR + (size_t)(b * ICH + i) * NST + n4 * 4;
    float4 Pv = { EXP2F(A[0] * cdt), EXP2F(A[1] * cdt),
                  EXP2F(A[2] * cdt), EXP2F(A[3] * cdt) };   // telescoped prod dA
    float4 Sv = { st[0], st[1], st[2], st[3] };
    *(float4*)(PArr + base)  = Pv;
    *(float4*)(SfArr + base) = Sv;
}

// ---------------- K5c: replay chunk with inline carry (k5b fused away),
// emit y fp16; LDS-staged inputs.
__global__ __launch_bounds__(256) void k5c_emit(
    const f16* __restrict__ dt,      // [M][I] f16
    const f16* __restrict__ h,       // [M][I] f16
    const f16* __restrict__ sgate,   // [M][I] f16
    const float* __restrict__ ssmp,  // [M][80]: B 48..63, C 64..79
    const float* __restrict__ A_log, // [I][16]
    const float* __restrict__ Dp,    // [I]
    const float* __restrict__ fg,    // [I]
    const float* __restrict__ PArr,  // [NCH][49152]
    const float* __restrict__ SfArr, // [NCH][49152]
    f16* __restrict__ yh)            // [M][I] fp16
{
    __shared__ float dts[CHS * 64];
    __shared__ float hs[CHS * 64];
    __shared__ float gs[CHS * 64];
    __shared__ float BC[CHS][32];    // [t][0..15]=B, [16..31]=C
    const int tid = threadIdx.x;
    const int n4 = tid & 3;
    const int il = tid >> 2;
    const int i0 = blockIdx.x * 64;
    const int i = i0 + il;
    const int c = blockIdx.y;
    const int b = blockIdx.z;
    const int s0 = c * CHS;
    const size_t row0 = (size_t)(b * S_LEN + s0) * ICH + i0;

    {   // stage dt/h/sgate: 32 rows x 64 ch, f16x8 per thread
        int r = tid >> 3, c8 = (tid & 7) * 8;
        size_t g_off = row0 + (size_t)r * ICH + c8;
        f16x8 dv = *(const f16x8*)(dt + g_off);
        f16x8 hv = *(const f16x8*)(h + g_off);
        f16x8 gv = *(const f16x8*)(sgate + g_off);
        #pragma unroll
        for (int j = 0; j < 8; ++j) {
            dts[r * 64 + c8 + j] = (float)dv[j];
            hs[r * 64 + c8 + j]  = (float)hv[j];
            gs[r * 64 + c8 + j]  = (float)gv[j];
        }
    }
    {   // stage B+C rows: 32 t x 32 floats = 256 float4
        int t = tid >> 3, q = tid & 7;
        *(float4*)&BC[t][q * 4] =
            *(const float4*)(ssmp + (size_t)(b * S_LEN + s0 + t) * 80 + 48 + q * 4);
    }

    const float L2E = 1.44269504088896f;
    float4 alv = *(const float4*)(A_log + i * NST + n4 * 4);
    float A[4] = { -__expf(alv.x) * L2E, -__expf(alv.y) * L2E,
                   -__expf(alv.z) * L2E, -__expf(alv.w) * L2E };
    const float Dv = Dp[i];
    const float fgv = fg[i];

    // ---- inline carry: scan P/Sf over chunks < c for this thread's 4 states.
    float st[4] = {};
    {
        const size_t sbase = (size_t)(b * ICH + i) * NST + n4 * 4;
        for (int cc = 0; cc < c; ++cc) {
            size_t a = (size_t)cc * CSTR + sbase;
            float4 p = *(const float4*)(PArr + a);
            float4 s = *(const float4*)(SfArr + a);
            st[0] = fmaf(p.x, st[0], s.x);
            st[1] = fmaf(p.y, st[1], s.y);
            st[2] = fmaf(p.z, st[2], s.z);
            st[3] = fmaf(p.w, st[3], s.w);
        }
    }

    f16* yout = yh + row0 + il;
    const bool last_chunk = (c == NCH - 1);
    __syncthreads();
    #pragma unroll 4
    for (int t = 0; t < CHS; ++t) {
        float dtv = dts[t * 64 + il];
        float hv  = hs[t * 64 + il];
        float4 Bv = *(const float4*)&BC[t][n4 * 4];
        float4 Cv = *(const float4*)&BC[t][16 + n4 * 4];
        float x = dtv * hv;
        float yp = 0.f;
        #pragma unroll
        for (int j = 0; j < 4; ++j) {
            float dA = EXP2F(A[j] * dtv);
            st[j] = fmaf(dA, st[j], x * (&Bv.x)[j]);
            yp = fmaf(st[j], (&Cv.x)[j], yp);
        }
        yp += __shfl_xor(yp, 1, 4);
        yp += __shfl_xor(yp, 2, 4);
        if (n4 == 0) {
            float yv = fmaf(hv, Dv, yp) * gs[t * 64 + il];
            if (last_chunk && t == CHS - 1) yv *= fgv;
            yout[(size_t)t * ICH] = (f16)yv;
        }
    }
}

// ---------------- K6: out_proj fp16 MFMA GEMM [4096,1536] @ [768,1536]^T
// tile 64m x 64n (grid 64x12 = 768 blocks, 3/CU); BK=32 double-buffered
// 2-phase prefetch. A via glds16; B reg-staged from fp32 OW with inline cvt
// (loads issued early, ds_write after MFMA). Plain fp32 stores.
__global__ __launch_bounds__(256) void k6m(
    const f16* __restrict__ Yh,     // [4096][1536]
    const float* __restrict__ OWf,  // [768][1536] fp32
    float* __restrict__ out)        // [M][768]
{
    __shared__ __align__(16) f16 As[2][64 * 32];
    __shared__ __align__(16) f16 Bs[2][64 * 32];
    const int tid = threadIdx.x;
    const int lane = tid & 63, wave = tid >> 6;
    const int quad = lane >> 4, l16 = lane & 15;
    const int wm = wave & 1, wn = wave >> 1;   // wn in 0..1
    const int m0 = blockIdx.x * 64, n0 = blockIdx.y * 64;
    const int l_row = lane >> 2, l_c8 = (lane & 3) * 8;

    const f16* Ag = Yh + (size_t)(m0 + wave * 16 + l_row) * ICH + l_c8;
    const int aOff = (wave * 16) * 32;
    const int brow = tid >> 2, bc8 = (tid & 3) * 8;   // 64 rows x 4 col8 slots
    const float* Bgf = OWf + (size_t)(n0 + brow) * ICH + bc8;
    float4 vb0, vb1;

#define K6_STAGEA(buf, kk) glds16(&As[buf][aOff], Ag + (kk))

#define K6_LOADB(kk)                                             \
    do {                                                         \
        vb0 = *(const float4*)(Bgf + (kk));                      \
        vb1 = *(const float4*)(Bgf + (kk) + 4);                  \
    } while (0)

#define K6_WRITEB(buf)                                                         \
    do {                                                                       \
        f16x8 o = { (f16)vb0.x, (f16)vb0.y, (f16)vb0.z, (f16)vb0.w,            \
                    (f16)vb1.x, (f16)vb1.y, (f16)vb1.z, (f16)vb1.w };          \
        *(f16x8*)&Bs[buf][brow * 32 + bc8] = o;                                \
    } while (0)

#define K6_COMPUTE(buf)                                                        \
    do {                                                                       \
        f16x8 af[2], bf[2];                                                    \
        _Pragma("unroll")                                                      \
        for (int mi = 0; mi < 2; ++mi)                                         \
            af[mi] = *(const f16x8*)&As[buf][(wm * 32 + mi * 16 + l16) * 32 + quad * 8]; \
        _Pragma("unroll")                                                      \
        for (int ni = 0; ni < 2; ++ni)                                         \
            bf[ni] = *(const f16x8*)&Bs[buf][(wn * 32 + ni * 16 + l16) * 32 + quad * 8]; \
        _Pragma("unroll")                                                      \
        for (int mi = 0; mi < 2; ++mi)                                         \
            _Pragma("unroll")                                                  \
            for (int ni = 0; ni < 2; ++ni)                                     \
                acc[mi][ni] = __builtin_amdgcn_mfma_f32_16x16x32_f16(          \
                    af[mi], bf[ni], acc[mi][ni], 0, 0, 0);                     \
    } while (0)

    // prologue: stage k=0..31 into buf0, drain
    K6_STAGEA(0, 0);
    K6_LOADB(0);
    K6_WRITEB(0);
    __syncthreads();

    f32x4 acc[2][2] = {};
    for (int k0 = 0; k0 < ICH; k0 += 64) {
        K6_STAGEA(1, k0 + 32);
        K6_LOADB(k0 + 32);
        K6_COMPUTE(0);
        K6_WRITEB(1);
        __syncthreads();           // buf1 ready (DMA + ds_writes drained)
        if (k0 + 64 < ICH) {
            K6_STAGEA(0, k0 + 64);
            K6_LOADB(k0 + 64);
        }
        K6_COMPUTE(1);
        if (k0 + 64 < ICH) K6_WRITEB(0);
        __syncthreads();
    }
#undef K6_STAGEA
#undef K6_LOADB
#undef K6_WRITEB
#undef K6_COMPUTE

    #pragma unroll
    for (int mi = 0; mi < 2; ++mi) {
        #pragma unroll
        for (int ni = 0; ni < 2; ++ni) {
            #pragma unroll
            for (int r = 0; r < 4; ++r) {
                int m = m0 + wm * 32 + mi * 16 + quad * 4 + r;
                int d = n0 + wn * 32 + ni * 16 + l16;
                out[(size_t)m * DMODEL + d] = acc[mi][ni][r];
            }
        }
    }
}

extern "C" void kernel_launch(void* const* d_in, const int* in_sizes, int n_in,
                              void* d_out, int out_size, void* d_ws, size_t ws_size,
                              hipStream_t stream) {
    const float* X     = (const float*)d_in[0];
    const float* W1    = (const float*)d_in[1];
    const float* CW    = (const float*)d_in[2];
    const float* CB    = (const float*)d_in[3];
    const float* XW    = (const float*)d_in[4];
    const float* DTW   = (const float*)d_in[5];
    const float* DTB   = (const float*)d_in[6];
    const float* ALOG  = (const float*)d_in[7];
    const float* DD    = (const float*)d_in[8];
    const float* OW    = (const float*)d_in[9];
    const float* ALPHA = (const float*)d_in[10];
    const float* FG    = (const float*)d_in[11];
    float* out = (float*)d_out;

    const size_t NBI = (size_t)MROWS * ICH;         // 6,291,456
    f16* hidden_h = (f16*)d_ws;                     // 12.58 MB
    f16* sgate_h  = hidden_h + NBI;
    f16* h_h      = sgate_h + NBI;
    f16* dt_h     = h_h + NBI;                      // f16
    float* ssmp   = (float*)(dt_h + NBI);           // 1.31 MB
    f16* Xh       = (f16*)(ssmp + (size_t)MROWS * 80);
    f16* W1h      = Xh + (size_t)MROWS * DMODEL;
    float* SfA    = (float*)(W1h + (size_t)2 * ICH * DMODEL);   // 12.58 MB
    // overlays: PArr on hidden (dead after k3m); yh on Xh/W1h (dead after k1m)
    float* PArr = (float*)hidden_h;                 // NCH*CSTR floats = 12.58 MB exact
    f16* yh     = Xh;                               // NBI f16 = 12.58 MB (fits Xh+W1h 15.7 MB)

    const int nX = MROWS * DMODEL;                  // 3,145,728
    const int nW1 = 2 * ICH * DMODEL;               // 2,359,296
    const int nS = MROWS * 80;                      // 327,680
    prep<<<dim3((nX + nW1 + nS) / 1024), 256, 0, stream>>>(X, Xh, nX, W1, W1h, nW1, ssmp);
    k1m<<<dim3(32, 24), 256, 0, stream>>>(Xh, W1h, hidden_h, sgate_h);
    k3m<<<dim3(32, 16), 256, 0, stream>>>(hidden_h, CW, CB, XW, h_h, ssmp);
    k4m<<<dim3(32, 12), 256, 0, stream>>>(ssmp, DTW, DTB, ALPHA, dt_h);
    k5a_chunk<<<dim3(24, NCH, 2), 256, 0, stream>>>(dt_h, h_h, ssmp, ALOG, PArr, SfA);
    k5c_emit<<<dim3(24, NCH, 2), 256, 0, stream>>>(dt_h, h_h, sgate_h, ssmp, ALOG, DD, FG, PArr, SfA, yh);
    k6m<<<dim3(64, 12), 256, 0, stream>>>(yh, OW, out);
}

// Round 7
// 240.383 us; speedup vs baseline: 1.0533x; 1.0533x over previous
//
#include <hip/hip_runtime.h>
#include <math.h>

// AdaptedMixer — Round 20: consolidation of proven configs.
//  - k5b restored (R19 inline-carry regressed k5c 40->54 us: 63-step dependent
//    load-fma chain). k5c back to CIn-based R18 interior.
//  - k1m back to 128x64 grid (32,48) = 6 blocks/CU (R13 finding: this
//    2-barrier loop needs >=6/CU for latency cover; R18's 128x128 @3/CU
//    was the hidden loss that canceled its gains).
//  - keep: prep fusion (memset+cvt2, -1 dispatch), k3m conv fusion,
//    k6m 64x64 reg-staged-B, k5a/k5c f16x8 staging.
// B=2 S=2048 Dm=768 I=1536 N=16 R=48 K=4.  M = B*S = 4096.

static constexpr int S_LEN  = 2048;
static constexpr int DMODEL = 768;
static constexpr int ICH    = 1536;
static constexpr int NST    = 16;
static constexpr int MROWS  = 4096;   // B*S
static constexpr int NCH    = 64;     // scan chunks
static constexpr int CHS    = 32;     // steps per chunk
static constexpr int CSTR   = 2 * ICH * NST;   // 49152: per-chunk summary stride

typedef _Float16 f16;
typedef f16 f16x8 __attribute__((ext_vector_type(8)));
typedef f16 f16x4 __attribute__((ext_vector_type(4)));
typedef f16 f16x2 __attribute__((ext_vector_type(2)));
typedef float f32x4 __attribute__((ext_vector_type(4)));

#if __has_builtin(__builtin_amdgcn_exp2f)
#define EXP2F(x) __builtin_amdgcn_exp2f(x)
#else
#define EXP2F(x) exp2f(x)
#endif

typedef __attribute__((address_space(3))) void lds_void;
typedef const __attribute__((address_space(1))) void glb_void;

__device__ __forceinline__ void glds16(f16* l, const f16* g) {
    __builtin_amdgcn_global_load_lds((glb_void*)g, (lds_void*)l, 16, 0, 0);
}

__device__ __forceinline__ float silu_f(float x) {
    return x / (1.0f + __expf(-x));
}

// ---------------- prep: cvt X->f16, cvt W1->f16, zero ssmp — one launch.
__global__ __launch_bounds__(256) void prep(
    const float* __restrict__ s0, f16* __restrict__ d0, int n0,
    const float* __restrict__ s1, f16* __restrict__ d1, int n1,
    float* __restrict__ z)          // ssmp, exact tail
{
    int i = (blockIdx.x * 256 + threadIdx.x) * 4;
    if (i < n0) {
        float4 v = *(const float4*)(s0 + i);
        f16x4 o = { (f16)v.x, (f16)v.y, (f16)v.z, (f16)v.w };
        *(f16x4*)(d0 + i) = o;
    } else if (i < n0 + n1) {
        int j = i - n0;
        float4 v = *(const float4*)(s1 + j);
        f16x4 o = { (f16)v.x, (f16)v.y, (f16)v.z, (f16)v.w };
        *(f16x4*)(d1 + j) = o;
    } else {
        int j = i - n0 - n1;
        float4 zv = {};
        *(float4*)(z + j) = zv;
    }
}

// ---------------- K1: in_proj fp16 MFMA GEMM [4096,768] @ [3072,768]^T
// tile 128m x 64n (grid 32x48 = 1536 blocks, 6/CU); BK=32 double-buffered
// 2-phase prefetch; waves 2x2, each 64m x 32n.
__global__ __launch_bounds__(256) void k1m(
    const f16* __restrict__ Xh,    // [4096][768]
    const f16* __restrict__ Wh,    // [3072][768]
    f16* __restrict__ hidden,      // [M][I]
    f16* __restrict__ sgate)       // [M][I] (silu applied)
{
    __shared__ __align__(16) f16 As[2][128 * 32];
    __shared__ __align__(16) f16 Bs[2][64 * 32];
    const int tid = threadIdx.x;
    const int lane = tid & 63, wave = tid >> 6;
    const int quad = lane >> 4, l16 = lane & 15;
    const int wm = wave & 1, wn = wave >> 1;   // wn in 0..1
    const int m0 = blockIdx.x * 128, n0 = blockIdx.y * 64;
    const int l_row = lane >> 2, l_c8 = (lane & 3) * 8;

    const f16* Ag = Xh + (size_t)(m0 + wave * 16 + l_row) * 768 + l_c8;
    const f16* Bg = Wh + (size_t)(n0 + wave * 16 + l_row) * 768 + l_c8;
    const int aLo = (wave * 16) * 32, aHi = (64 + wave * 16) * 32;
    const int bOff = (wave * 16) * 32;

#define K1_STAGE(buf, kk)                                        \
    do {                                                         \
        glds16(&As[buf][aLo], Ag + (kk));                        \
        glds16(&As[buf][aHi], Ag + (size_t)64 * 768 + (kk));     \
        glds16(&Bs[buf][bOff], Bg + (kk));                       \
    } while (0)

#define K1_COMPUTE(buf)                                                        \
    do {                                                                       \
        f16x8 af[4], bf[2];                                                    \
        _Pragma("unroll")                                                      \
        for (int mi = 0; mi < 4; ++mi)                                         \
            af[mi] = *(const f16x8*)&As[buf][(wm * 64 + mi * 16 + l16) * 32 + quad * 8]; \
        _Pragma("unroll")                                                      \
        for (int ni = 0; ni < 2; ++ni)                                         \
            bf[ni] = *(const f16x8*)&Bs[buf][(wn * 32 + ni * 16 + l16) * 32 + quad * 8]; \
        _Pragma("unroll")                                                      \
        for (int mi = 0; mi < 4; ++mi)                                         \
            _Pragma("unroll")                                                  \
            for (int ni = 0; ni < 2; ++ni)                                     \
                acc[mi][ni] = __builtin_amdgcn_mfma_f32_16x16x32_f16(          \
                    af[mi], bf[ni], acc[mi][ni], 0, 0, 0);                     \
    } while (0)

    // prologue: stage k=0..31 into buf0, drain
    K1_STAGE(0, 0);
    __syncthreads();

    f32x4 acc[4][2] = {};
    for (int k0 = 0; k0 < 768; k0 += 64) {
        K1_STAGE(1, k0 + 32);
        K1_COMPUTE(0);
        __syncthreads();           // vmcnt(0): buf1 ready; all waves done with buf0
        if (k0 + 64 < 768) K1_STAGE(0, k0 + 64);
        K1_COMPUTE(1);
        __syncthreads();           // vmcnt(0): buf0 ready; all waves done with buf1
    }
#undef K1_STAGE
#undef K1_COMPUTE

    const bool isGate = (n0 >= ICH);
    f16* outp = isGate ? sgate : hidden;
    const int e0 = (isGate ? (n0 - ICH) : n0) + wn * 32 + l16;
    #pragma unroll
    for (int mi = 0; mi < 4; ++mi) {
        #pragma unroll
        for (int ni = 0; ni < 2; ++ni) {
            #pragma unroll
            for (int r = 0; r < 4; ++r) {
                int m = m0 + wm * 64 + mi * 16 + quad * 4 + r;
                int e = e0 + ni * 16;
                float v = acc[mi][ni][r];
                if (isGate) v = silu_f(v);
                outp[(size_t)m * ICH + e] = (f16)v;
            }
        }
    }
}

// ---------------- K3: conv+bias+silu fused into A-stage, emits h; then
// x_proj fp16 MFMA GEMM -> ssmp[m][e] (+=, atomics), ksplit x16.
__global__ __launch_bounds__(256) void k3m(
    const f16* __restrict__ hidden,   // [M][I] f16 (pre-conv)
    const float* __restrict__ conv_w, // [I][4]
    const float* __restrict__ conv_b, // [I]
    const float* __restrict__ xw,     // [80][I] fp32
    f16* __restrict__ h,              // [M][I] f16 out (post conv+silu)
    float* __restrict__ ssmp)         // [M][80], pre-zeroed
{
    __shared__ __align__(16) f16 Ah[128 * 32];
    __shared__ __align__(16) f16 Bh[80 * 32];
    __shared__ float4 cwv[96];
    __shared__ float  cbv[96];
    const int tid = threadIdx.x;
    const int lane = tid & 63, wave = tid >> 6;
    const int quad = lane >> 4, l16 = lane & 15;
    const int m0 = blockIdx.x * 128;
    const int kbeg = blockIdx.y * 96;

    if (tid < 96) {
        cwv[tid] = *(const float4*)(conv_w + (size_t)(kbeg + tid) * 4);
        cbv[tid] = conv_b[kbeg + tid];
    }

    f32x4 acc[2][5] = {};
    for (int k0 = kbeg; k0 < kbeg + 96; k0 += 32) {
        __syncthreads();
        // ---- A-stage: compute h = silu(conv(hidden)+b) for 128 rows x 32 ch,
        // write to LDS (MFMA A operand) and to global h.
        #pragma unroll
        for (int it = 0; it < 2; ++it) {
            int slot = tid + it * 256;            // 512 slots: 128 rows x 4 col8
            int r_ = slot >> 2, c_ = (slot & 3) * 8;
            int gm = m0 + r_, c = k0 + c_;
            int s = gm & (S_LEN - 1);
            const f16* bp = hidden + (size_t)gm * ICH + c;
            f16x8 x0 = *(const f16x8*)bp;
            f16x8 x1 = *(const f16x8*)(bp - (s >= 1 ? ICH : 0));
            f16x8 x2 = *(const f16x8*)(bp - (s >= 2 ? 2 * ICH : 0));
            f16x8 x3 = *(const f16x8*)(bp - (s >= 3 ? 3 * ICH : 0));
            f16x8 o;
            #pragma unroll
            for (int j = 0; j < 8; ++j) {
                int ci = (k0 - kbeg) + c_ + j;
                float4 w = cwv[ci];
                float v1 = (s >= 1) ? (float)x1[j] : 0.f;
                float v2 = (s >= 2) ? (float)x2[j] : 0.f;
                float v3 = (s >= 3) ? (float)x3[j] : 0.f;
                float r = cbv[ci] + w.x * v3 + w.y * v2 + w.z * v1 + w.w * (float)x0[j];
                o[j] = (f16)silu_f(r);
            }
            *(f16x8*)&Ah[r_ * 32 + c_] = o;
            *(f16x8*)(h + (size_t)gm * ICH + c) = o;
        }
        // ---- B-stage: 80 rows x 32 cols fp32 -> f16
        {
            int c4 = (tid & 7) * 4;
            for (int r = tid >> 3; r < 80; r += 32) {
                float4 v = *(const float4*)(xw + (size_t)r * ICH + k0 + c4);
                f16x4 o = { (f16)v.x, (f16)v.y, (f16)v.z, (f16)v.w };
                *(f16x4*)&Bh[r * 32 + c4] = o;
            }
        }
        __syncthreads();
        f16x8 af[2], bf[5];
        #pragma unroll
        for (int mi = 0; mi < 2; ++mi)
            af[mi] = *(const f16x8*)&Ah[(wave * 32 + mi * 16 + l16) * 32 + quad * 8];
        #pragma unroll
        for (int j = 0; j < 5; ++j)
            bf[j] = *(const f16x8*)&Bh[(j * 16 + l16) * 32 + quad * 8];
        #pragma unroll
        for (int mi = 0; mi < 2; ++mi)
            #pragma unroll
            for (int j = 0; j < 5; ++j)
                acc[mi][j] = __builtin_amdgcn_mfma_f32_16x16x32_f16(
                    af[mi], bf[j], acc[mi][j], 0, 0, 0);
    }
    #pragma unroll
    for (int mi = 0; mi < 2; ++mi) {
        #pragma unroll
        for (int j = 0; j < 5; ++j) {
            #pragma unroll
            for (int r = 0; r < 4; ++r) {
                int m = m0 + wave * 32 + mi * 16 + quad * 4 + r;
                atomicAdd(ssmp + (size_t)m * 80 + j * 16 + l16, acc[mi][j][r]);
            }
        }
    }
}

// ---------------- K4: dt = softplus(ts @ dtw^T + b) via fp16 MFMA, K=48 padded to 64.
__global__ __launch_bounds__(256) void k4m(
    const float* __restrict__ ssmp,   // [M][80] (ts = cols 0..47)
    const float* __restrict__ dtw,    // [I][48]
    const float* __restrict__ dtb,    // [I]
    const float* __restrict__ alpha,  // [I]
    f16* __restrict__ dt)             // [M][I] f16
{
    __shared__ __align__(16) f16 As[128 * 72];   // [row][72] (64 K + 8 pad)
    __shared__ __align__(16) f16 Bs[128 * 72];
    const int tid = threadIdx.x;
    const int lane = tid & 63, wave = tid >> 6;
    const int quad = lane >> 4, l16 = lane & 15;
    const int wm = wave & 1, wn = wave >> 1;
    const int m0 = blockIdx.x * 128, n0 = blockIdx.y * 128;
    const int srow = tid >> 1;          // 0..127
    const int shalf = tid & 1;          // 0..1 -> cols [0,24) or [24,48)

    {   // stage A (ts) and B (dtw), cvt to fp16, zero-pad cols 48..63
        const float* sa = ssmp + (size_t)(m0 + srow) * 80 + shalf * 24;
        const float* sb = dtw + (size_t)(n0 + srow) * 48 + shalf * 24;
        f16* da = &As[srow * 72 + shalf * 24];
        f16* db = &Bs[srow * 72 + shalf * 24];
        #pragma unroll
        for (int j = 0; j < 6; ++j) {
            float4 va = *(const float4*)(sa + 4 * j);
            float4 vb = *(const float4*)(sb + 4 * j);
            f16x4 oa = { (f16)va.x, (f16)va.y, (f16)va.z, (f16)va.w };
            f16x4 ob = { (f16)vb.x, (f16)vb.y, (f16)vb.z, (f16)vb.w };
            *(f16x4*)(da + 4 * j) = oa;
            *(f16x4*)(db + 4 * j) = ob;
        }
        if (shalf) {
            f16x8 z = {};
            *(f16x8*)&As[srow * 72 + 48] = z;
            *(f16x8*)&As[srow * 72 + 56] = z;
            *(f16x8*)&Bs[srow * 72 + 48] = z;
            *(f16x8*)&Bs[srow * 72 + 56] = z;
        }
    }
    __syncthreads();

    f32x4 acc[4][4] = {};
    #pragma unroll
    for (int ks = 0; ks < 2; ++ks) {
        f16x8 af[4], bf[4];
        #pragma unroll
        for (int mi = 0; mi < 4; ++mi)
            af[mi] = *(const f16x8*)&As[(wm * 64 + mi * 16 + l16) * 72 + ks * 32 + quad * 8];
        #pragma unroll
        for (int ni = 0; ni < 4; ++ni)
            bf[ni] = *(const f16x8*)&Bs[(wn * 64 + ni * 16 + l16) * 72 + ks * 32 + quad * 8];
        #pragma unroll
        for (int mi = 0; mi < 4; ++mi)
            #pragma unroll
            for (int ni = 0; ni < 4; ++ni)
                acc[mi][ni] = __builtin_amdgcn_mfma_f32_16x16x32_f16(
                    af[mi], bf[ni], acc[mi][ni], 0, 0, 0);
    }

    #pragma unroll
    for (int ni = 0; ni < 4; ++ni) {
        int e = n0 + wn * 64 + ni * 16 + l16;
        float bias = dtb[e];
        float al = alpha[e];
        #pragma unroll
        for (int mi = 0; mi < 4; ++mi) {
            #pragma unroll
            for (int r = 0; r < 4; ++r) {
                int m = m0 + wm * 64 + mi * 16 + quad * 4 + r;
                float x = acc[mi][ni][r] + bias;
                float sp = (x > 20.0f) ? x : __logf(1.0f + __expf(x));
                if ((m & (S_LEN - 1)) == S_LEN - 1) sp *= al;
                dt[(size_t)m * ICH + e] = (f16)sp;
            }
        }
    }
}

// ---------------- K5a: per-chunk summary, LDS-staged dt/h/B; coalesced float4 P/Sf.
__global__ __launch_bounds__(256) void k5a_chunk(
    const f16* __restrict__ dt,      // [M][I] f16
    const f16* __restrict__ h,       // [M][I] f16
    const float* __restrict__ ssmp,  // [M][80]: B cols 48..63
    const float* __restrict__ A_log, // [I][16]
    float* __restrict__ PArr,        // [NCH][B*I*16]
    float* __restrict__ SfArr)       // [NCH][B*I*16]
{
    __shared__ float dts[CHS * 64];
    __shared__ float hs[CHS * 64];
    __shared__ float Bc[CHS][16];
    const int tid = threadIdx.x;
    const int n4 = tid & 3;
    const int il = tid >> 2;         // 0..63
    const int i0 = blockIdx.x * 64;
    const int i = i0 + il;
    const int c = blockIdx.y;
    const int b = blockIdx.z;
    const int s0 = c * CHS;
    const size_t row0 = (size_t)(b * S_LEN + s0) * ICH + i0;

    {   // stage dt/h: 32 rows x 64 ch, f16x8 per thread (16B/lane)
        int r = tid >> 3, c8 = (tid & 7) * 8;
        size_t g_off = row0 + (size_t)r * ICH + c8;
        f16x8 dv = *(const f16x8*)(dt + g_off);
        f16x8 hv = *(const f16x8*)(h + g_off);
        #pragma unroll
        for (int j = 0; j < 8; ++j) {
            dts[r * 64 + c8 + j] = (float)dv[j];
            hs[r * 64 + c8 + j]  = (float)hv[j];
        }
    }
    if (tid < CHS * 4) {     // stage B rows: 32 t x 16 floats
        int t = tid >> 2, q = tid & 3;
        *(float4*)&Bc[t][q * 4] =
            *(const float4*)(ssmp + (size_t)(b * S_LEN + s0 + t) * 80 + 48 + q * 4);
    }

    const float L2E = 1.44269504088896f;
    float4 alv = *(const float4*)(A_log + i * NST + n4 * 4);
    float A[4] = { -__expf(alv.x) * L2E, -__expf(alv.y) * L2E,
                   -__expf(alv.z) * L2E, -__expf(alv.w) * L2E };
    float st[4] = {};
    float cdt = 0.f;
    __syncthreads();
    #pragma unroll 4
    for (int t = 0; t < CHS; ++t) {
        float dtv = dts[t * 64 + il];
        float hv  = hs[t * 64 + il];
        float4 Bv = *(const float4*)&Bc[t][n4 * 4];
        cdt += dtv;
        float x = dtv * hv;
        #pragma unroll
        for (int j = 0; j < 4; ++j) {
            float dA = EXP2F(A[j] * dtv);
            st[j] = fmaf(dA, st[j], x * (&Bv.x)[j]);
        }
    }
    size_t base = (size_t)c * CSTR + (size_t)(b * ICH + i) * NST + n4 * 4;
    float4 Pv = { EXP2F(A[0] * cdt), EXP2F(A[1] * cdt),
                  EXP2F(A[2] * cdt), EXP2F(A[3] * cdt) };   // telescoped prod dA
    float4 Sv = { st[0], st[1], st[2], st[3] };
    *(float4*)(PArr + base)  = Pv;
    *(float4*)(SfArr + base) = Sv;
}

// ---------------- K5b: combine chunk summaries into carry-in per chunk.
__global__ __launch_bounds__(256) void k5b_carry(
    const float* PArr,       // [NCH][49152]
    const float* __restrict__ SfArr,
    float* CIn)              // aliases PArr
{
    int idx = blockIdx.x * 256 + threadIdx.x;   // over B*I*16 = 49152
    float p[NCH], s[NCH];
    #pragma unroll
    for (int c = 0; c < NCH; ++c) {
        size_t a = (size_t)c * CSTR + idx;
        p[c] = PArr[a];
        s[c] = SfArr[a];
    }
    float carry = 0.f;
    #pragma unroll
    for (int c = 0; c < NCH; ++c) {
        CIn[(size_t)c * CSTR + idx] = carry;
        carry = fmaf(p[c], carry, s[c]);
    }
}

// ---------------- K5c: replay chunk with carry-in, emit y fp16; LDS-staged inputs
__global__ __launch_bounds__(256) void k5c_emit(
    const f16* __restrict__ dt,      // [M][I] f16
    const f16* __restrict__ h,       // [M][I] f16
    const f16* __restrict__ sgate,   // [M][I] f16
    const float* __restrict__ ssmp,  // [M][80]: B 48..63, C 64..79
    const float* __restrict__ A_log, // [I][16]
    const float* __restrict__ Dp,    // [I]
    const float* __restrict__ fg,    // [I]
    const float* __restrict__ CIn,   // [NCH][49152]
    f16* __restrict__ yh)            // [M][I] fp16
{
    __shared__ float dts[CHS * 64];
    __shared__ float hs[CHS * 64];
    __shared__ float gs[CHS * 64];
    __shared__ float BC[CHS][32];    // [t][0..15]=B, [16..31]=C
    const int tid = threadIdx.x;
    const int n4 = tid & 3;
    const int il = tid >> 2;
    const int i0 = blockIdx.x * 64;
    const int i = i0 + il;
    const int c = blockIdx.y;
    const int b = blockIdx.z;
    const int s0 = c * CHS;
    const size_t row0 = (size_t)(b * S_LEN + s0) * ICH + i0;

    {   // stage dt/h/sgate: 32 rows x 64 ch, f16x8 per thread
        int r = tid >> 3, c8 = (tid & 7) * 8;
        size_t g_off = row0 + (size_t)r * ICH + c8;
        f16x8 dv = *(const f16x8*)(dt + g_off);
        f16x8 hv = *(const f16x8*)(h + g_off);
        f16x8 gv = *(const f16x8*)(sgate + g_off);
        #pragma unroll
        for (int j = 0; j < 8; ++j) {
            dts[r * 64 + c8 + j] = (float)dv[j];
            hs[r * 64 + c8 + j]  = (float)hv[j];
            gs[r * 64 + c8 + j]  = (float)gv[j];
        }
    }
    {   // stage B+C rows: 32 t x 32 floats = 256 float4
        int t = tid >> 3, q = tid & 7;
        *(float4*)&BC[t][q * 4] =
            *(const float4*)(ssmp + (size_t)(b * S_LEN + s0 + t) * 80 + 48 + q * 4);
    }

    const float L2E = 1.44269504088896f;
    float4 alv = *(const float4*)(A_log + i * NST + n4 * 4);
    float A[4] = { -__expf(alv.x) * L2E, -__expf(alv.y) * L2E,
                   -__expf(alv.z) * L2E, -__expf(alv.w) * L2E };
    const float Dv = Dp[i];
    const float fgv = fg[i];
    float4 civ = *(const float4*)(CIn + (size_t)c * CSTR + (size_t)(b * ICH + i) * NST + n4 * 4);
    float st[4] = { civ.x, civ.y, civ.z, civ.w };
    f16* yout = yh + row0 + il;
    const bool last_chunk = (c == NCH - 1);
    __syncthreads();
    #pragma unroll 4
    for (int t = 0; t < CHS; ++t) {
        float dtv = dts[t * 64 + il];
        float hv  = hs[t * 64 + il];
        float4 Bv = *(const float4*)&BC[t][n4 * 4];
        float4 Cv = *(const float4*)&BC[t][16 + n4 * 4];
        float x = dtv * hv;
        float yp = 0.f;
        #pragma unroll
        for (int j = 0; j < 4; ++j) {
            float dA = EXP2F(A[j] * dtv);
            st[j] = fmaf(dA, st[j], x * (&Bv.x)[j]);
            yp = fmaf(st[j], (&Cv.x)[j], yp);
        }
        yp += __shfl_xor(yp, 1, 4);
        yp += __shfl_xor(yp, 2, 4);
        if (n4 == 0) {
            float yv = fmaf(hv, Dv, yp) * gs[t * 64 + il];
            if (last_chunk && t == CHS - 1) yv *= fgv;
            yout[(size_t)t * ICH] = (f16)yv;
        }
    }
}

// ---------------- K6: out_proj fp16 MFMA GEMM [4096,1536] @ [768,1536]^T
// tile 64m x 64n (grid 64x12 = 768 blocks, 3/CU); BK=32 double-buffered
// 2-phase prefetch. A via glds16; B reg-staged from fp32 OW with inline cvt
// (loads issued early, ds_write after MFMA). Plain fp32 stores.
__global__ __launch_bounds__(256) void k6m(
    const f16* __restrict__ Yh,     // [4096][1536]
    const float* __restrict__ OWf,  // [768][1536] fp32
    float* __restrict__ out)        // [M][768]
{
    __shared__ __align__(16) f16 As[2][64 * 32];
    __shared__ __align__(16) f16 Bs[2][64 * 32];
    const int tid = threadIdx.x;
    const int lane = tid & 63, wave = tid >> 6;
    const int quad = lane >> 4, l16 = lane & 15;
    const int wm = wave & 1, wn = wave >> 1;   // wn in 0..1
    const int m0 = blockIdx.x * 64, n0 = blockIdx.y * 64;
    const int l_row = lane >> 2, l_c8 = (lane & 3) * 8;

    const f16* Ag = Yh + (size_t)(m0 + wave * 16 + l_row) * ICH + l_c8;
    const int aOff = (wave * 16) * 32;
    const int brow = tid >> 2, bc8 = (tid & 3) * 8;   // 64 rows x 4 col8 slots
    const float* Bgf = OWf + (size_t)(n0 + brow) * ICH + bc8;
    float4 vb0, vb1;

#define K6_STAGEA(buf, kk) glds16(&As[buf][aOff], Ag + (kk))

#define K6_LOADB(kk)                                             \
    do {                                                         \
        vb0 = *(const float4*)(Bgf + (kk));                      \
        vb1 = *(const float4*)(Bgf + (kk) + 4);                  \
    } while (0)

#define K6_WRITEB(buf)                                                         \
    do {                                                                       \
        f16x8 o = { (f16)vb0.x, (f16)vb0.y, (f16)vb0.z, (f16)vb0.w,            \
                    (f16)vb1.x, (f16)vb1.y, (f16)vb1.z, (f16)vb1.w };          \
        *(f16x8*)&Bs[buf][brow * 32 + bc8] = o;                                \
    } while (0)

#define K6_COMPUTE(buf)                                                        \
    do {                                                                       \
        f16x8 af[2], bf[2];                                                    \
        _Pragma("unroll")                                                      \
        for (int mi = 0; mi < 2; ++mi)                                         \
            af[mi] = *(const f16x8*)&As[buf][(wm * 32 + mi * 16 + l16) * 32 + quad * 8]; \
        _Pragma("unroll")                                                      \
        for (int ni = 0; ni < 2; ++ni)                                         \
            bf[ni] = *(const f16x8*)&Bs[buf][(wn * 32 + ni * 16 + l16) * 32 + quad * 8]; \
        _Pragma("unroll")                                                      \
        for (int mi = 0; mi < 2; ++mi)                                         \
            _Pragma("unroll")                                                  \
            for (int ni = 0; ni < 2; ++ni)                                     \
                acc[mi][ni] = __builtin_amdgcn_mfma_f32_16x16x32_f16(          \
                    af[mi], bf[ni], acc[mi][ni], 0, 0, 0);                     \
    } while (0)

    // prologue: stage k=0..31 into buf0, drain
    K6_STAGEA(0, 0);
    K6_LOADB(0);
    K6_WRITEB(0);
    __syncthreads();

    f32x4 acc[2][2] = {};
    for (int k0 = 0; k0 < ICH; k0 += 64) {
        K6_STAGEA(1, k0 + 32);
        K6_LOADB(k0 + 32);
        K6_COMPUTE(0);
        K6_WRITEB(1);
        __syncthreads();           // buf1 ready (DMA + ds_writes drained)
        if (k0 + 64 < ICH) {
            K6_STAGEA(0, k0 + 64);
            K6_LOADB(k0 + 64);
        }
        K6_COMPUTE(1);
        if (k0 + 64 < ICH) K6_WRITEB(0);
        __syncthreads();
    }
#undef K6_STAGEA
#undef K6_LOADB
#undef K6_WRITEB
#undef K6_COMPUTE

    #pragma unroll
    for (int mi = 0; mi < 2; ++mi) {
        #pragma unroll
        for (int ni = 0; ni < 2; ++ni) {
            #pragma unroll
            for (int r = 0; r < 4; ++r) {
                int m = m0 + wm * 32 + mi * 16 + quad * 4 + r;
                int d = n0 + wn * 32 + ni * 16 + l16;
                out[(size_t)m * DMODEL + d] = acc[mi][ni][r];
            }
        }
    }
}

extern "C" void kernel_launch(void* const* d_in, const int* in_sizes, int n_in,
                              void* d_out, int out_size, void* d_ws, size_t ws_size,
                              hipStream_t stream) {
    const float* X     = (const float*)d_in[0];
    const float* W1    = (const float*)d_in[1];
    const float* CW    = (const float*)d_in[2];
    const float* CB    = (const float*)d_in[3];
    const float* XW    = (const float*)d_in[4];
    const float* DTW   = (const float*)d_in[5];
    const float* DTB   = (const float*)d_in[6];
    const float* ALOG  = (const float*)d_in[7];
    const float* DD    = (const float*)d_in[8];
    const float* OW    = (const float*)d_in[9];
    const float* ALPHA = (const float*)d_in[10];
    const float* FG    = (const float*)d_in[11];
    float* out = (float*)d_out;

    const size_t NBI = (size_t)MROWS * ICH;         // 6,291,456
    f16* hidden_h = (f16*)d_ws;                     // 12.58 MB
    f16* sgate_h  = hidden_h + NBI;
    f16* h_h      = sgate_h + NBI;
    f16* dt_h     = h_h + NBI;                      // f16
    float* ssmp   = (float*)(dt_h + NBI);           // 1.31 MB
    f16* Xh       = (f16*)(ssmp + (size_t)MROWS * 80);
    f16* W1h      = Xh + (size_t)MROWS * DMODEL;
    float* SfA    = (float*)(W1h + (size_t)2 * ICH * DMODEL);   // 12.58 MB
    // overlays: PArr/CIn on hidden (dead after k3m); yh on Sf (dead after k5b)
    float* PArr = (float*)hidden_h;                 // NCH*CSTR floats = 12.58 MB exact
    float* CIn  = PArr;
    f16* yh     = (f16*)SfA;                        // NBI f16 = 12.58 MB exact

    const int nX = MROWS * DMODEL;                  // 3,145,728
    const int nW1 = 2 * ICH * DMODEL;               // 2,359,296
    const int nS = MROWS * 80;                      // 327,680
    prep<<<dim3((nX + nW1 + nS) / 1024), 256, 0, stream>>>(X, Xh, nX, W1, W1h, nW1, ssmp);
    k1m<<<dim3(32, 48), 256, 0, stream>>>(Xh, W1h, hidden_h, sgate_h);
    k3m<<<dim3(32, 16), 256, 0, stream>>>(hidden_h, CW, CB, XW, h_h, ssmp);
    k4m<<<dim3(32, 12), 256, 0, stream>>>(ssmp, DTW, DTB, ALPHA, dt_h);
    k5a_chunk<<<dim3(24, NCH, 2), 256, 0, stream>>>(dt_h, h_h, ssmp, ALOG, PArr, SfA);
    k5b_carry<<<dim3(192), 256, 0, stream>>>(PArr, SfA, CIn);
    k5c_emit<<<dim3(24, NCH, 2), 256, 0, stream>>>(dt_h, h_h, sgate_h, ssmp, ALOG, DD, FG, CIn, yh);
    k6m<<<dim3(64, 12), 256, 0, stream>>>(yh, OW, out);
}